// Round 3
// baseline (50.853 us; speedup 1.0000x reference)
//
#include <hip/hip_runtime.h>

#define NE 19
#define NEDGE 361
#define CIN 64
#define PG 8
#define ROWS (NE*PG)      // 152 rows per block
#define MTILES 10         // ceil(152/16)
#define NTHREADS 256
#define STRIDE 256        // bytes per LDS row: 128 bf16 (mixed cols 0-63, raw 64-127) OR 64 f32 (bounce)

typedef float f32x4 __attribute__((ext_vector_type(4)));
typedef float f32x2 __attribute__((ext_vector_type(2)));
typedef unsigned short u16x2 __attribute__((ext_vector_type(2)));
typedef unsigned short u16x4 __attribute__((ext_vector_type(4)));
typedef unsigned short u16x8 __attribute__((ext_vector_type(8)));
typedef __bf16 bf16x8 __attribute__((ext_vector_type(8)));

__device__ __forceinline__ unsigned short f2bf(float f) {
  unsigned u = __builtin_bit_cast(unsigned, f);
  return (unsigned short)((u + 0x7FFFu + ((u >> 16) & 1u)) >> 16);
}
__device__ __forceinline__ float rdlane(float v, int l) {
  return __builtin_bit_cast(float, __builtin_amdgcn_readlane(__builtin_bit_cast(int, v), l));
}
__device__ __forceinline__ int swz(int row, int byteoff) {
  return row * STRIDE + (byteoff ^ ((row & 7) << 4));
}

__global__ __launch_bounds__(NTHREADS, 4) void gconv_kernel(
    const float* __restrict__ x, const float* __restrict__ ew,
    const float* __restrict__ Wrel, const float* __restrict__ Wroot,
    const float* __restrict__ bias, float* __restrict__ out)
{
  __shared__ __align__(16) unsigned char xc[ROWS * STRIDE];  // 38912 B -> 4 blocks/CU

  const int t = threadIdx.x;
  const int lane = t & 63;
  const int wv = t >> 6;
  const int row0 = blockIdx.x * ROWS;
  const float* xg = x + (long long)row0 * CIN;

  // ---- Phase A (no barrier needed): stage raw x -> xc bytes [128,256) as bf16
  #pragma unroll
  for (int p = 0; p < 10; ++p) {
    int q = p * NTHREADS + t;
    if (q < ROWS * 16) {
      int r = q >> 4, c = q & 15;
      f32x4 v = *(const f32x4*)(xg + q * 4);
      u16x4 h;
      h[0]=f2bf(v[0]); h[1]=f2bf(v[1]); h[2]=f2bf(v[2]); h[3]=f2bf(v[3]);
      *(u16x4*)(&xc[swz(r, 128 + c * 8)]) = h;
    }
  }

  // ---- Phase B (parallel with A, disjoint LDS bytes): mix -> xc bytes [0,128)
  // A[i][j] = softplus(ew[j*19+i]); held as areg[i] with lane j = A[i][j].
  // Thread = (graph g=t>>5, channel pair c2=t&31); x read from global (L2).
  {
    const int g = t >> 5, c2 = t & 31;
    const int rb = g * NE;
    float areg[NE];
    #pragma unroll
    for (int i = 0; i < NE; ++i) {
      float z = (lane < NE) ? ew[lane * NE + i] : 0.0f;
      areg[i] = fmaxf(z, 0.0f) + log1pf(expf(-fabsf(z)));
    }
    float acc0[NE], acc1[NE];
    #pragma unroll
    for (int i = 0; i < NE; ++i) { acc0[i] = 0.f; acc1[i] = 0.f; }
    for (int j = 0; j < NE; ++j) {          // j uniform -> readlane legal
      f32x2 xv = *(const f32x2*)(xg + (rb + j) * CIN + c2 * 2);
      #pragma unroll
      for (int i = 0; i < NE; ++i) {
        float a = rdlane(areg[i], j);
        acc0[i] = fmaf(a, xv[0], acc0[i]);
        acc1[i] = fmaf(a, xv[1], acc1[i]);
      }
    }
    #pragma unroll
    for (int i = 0; i < NE; ++i) {
      u16x2 h; h[0] = f2bf(acc0[i]); h[1] = f2bf(acc1[i]);
      *(u16x2*)(&xc[swz(rb + i, c2 * 4)]) = h;
    }
  }
  __syncthreads();   // barrier 1: staging+mix visible to all

  // ---- B fragments (block-uniform, L2/L3-hot) loaded after mix to cut VGPR peak
  // Wc[k][n]: k<64 -> Wrel[n][k] (mixed), k>=64 -> Wroot[n][k-64] (raw)
  u16x8 bfrag[4][4];
  float biasv[4];
  {
    const int jl = lane & 15;
    const int k0 = (lane >> 4) * 8;
    #pragma unroll
    for (int nt = 0; nt < 4; ++nt) biasv[nt] = bias[nt * 16 + jl];
    #pragma unroll
    for (int kt = 0; kt < 4; ++kt) {
      const float* Wsrc = (kt < 2) ? Wrel : Wroot;
      const float* p = Wsrc + ((kt & 1) * 32 + k0);
      #pragma unroll
      for (int nt = 0; nt < 4; ++nt) {
        const float* q = p + (nt * 16 + jl) * CIN;
        f32x4 a = *(const f32x4*)q;
        f32x4 b = *(const f32x4*)(q + 4);
        u16x8 h;
        h[0]=f2bf(a[0]); h[1]=f2bf(a[1]); h[2]=f2bf(a[2]); h[3]=f2bf(a[3]);
        h[4]=f2bf(b[0]); h[5]=f2bf(b[1]); h[6]=f2bf(b[2]); h[7]=f2bf(b[3]);
        bfrag[kt][nt] = h;
      }
    }
  }

  // ---- GEMM: out-tile = XC[152x128] @ Wc[128x64]; D -> f32 bounce in xc.
  // Tiles are wave-disjoint row sets: D f32 writes race-free vs other waves' reads.
  const int lr = lane & 15;
  const int hg = lane >> 4;
  for (int mt = wv; mt < MTILES; mt += 4) {
    const int r0 = mt * 16;
    int rr = r0 + lr; if (rr >= ROWS) rr = ROWS - 1;   // dup row; D row m depends only on A row m
    u16x8 af[4];
    #pragma unroll
    for (int kt = 0; kt < 4; ++kt)
      af[kt] = *(const u16x8*)(&xc[swz(rr, kt * 64 + hg * 16)]);
    f32x4 acc[4];
    #pragma unroll
    for (int nt = 0; nt < 4; ++nt) { acc[nt][0]=0.f; acc[nt][1]=0.f; acc[nt][2]=0.f; acc[nt][3]=0.f; }
    #pragma unroll
    for (int kt = 0; kt < 4; ++kt)
      #pragma unroll
      for (int nt = 0; nt < 4; ++nt)
        acc[nt] = __builtin_amdgcn_mfma_f32_16x16x32_bf16(
            __builtin_bit_cast(bf16x8, af[kt]),
            __builtin_bit_cast(bf16x8, bfrag[kt][nt]), acc[nt], 0, 0, 0);
    // D: col = nt*16+lr, row = r0 + hg*4 + b  -> f32 at byte (col*4)^swz
    #pragma unroll
    for (int nt = 0; nt < 4; ++nt)
      #pragma unroll
      for (int b = 0; b < 4; ++b) {
        int row = r0 + hg * 4 + b;
        if (row < ROWS)
          *(float*)(&xc[swz(row, (nt * 16 + lr) * 4)]) = acc[nt][b] + biasv[nt];
      }
  }
  __syncthreads();   // barrier 2: bounce complete

  // ---- Epilogue: coalesced f32x4 stores (1 KB contiguous per wave instr)
  #pragma unroll
  for (int p = 0; p < 10; ++p) {
    int q = p * NTHREADS + t;
    if (q < ROWS * 16) {
      int r = q >> 4, c = q & 15;
      f32x4 v = *(const f32x4*)(&xc[swz(r, c * 16)]);
      *(f32x4*)(out + ((long long)row0 + r) * CIN + c * 4) = v;
    }
  }
}

extern "C" void kernel_launch(void* const* d_in, const int* in_sizes, int n_in,
                              void* d_out, int out_size, void* d_ws, size_t ws_size,
                              hipStream_t stream) {
  const float* x    = (const float*)d_in[0];
  const float* ew   = (const float*)d_in[1];
  const float* Wrel = (const float*)d_in[2];
  const float* Wroot= (const float*)d_in[3];
  const float* bias = (const float*)d_in[4];
  float* out = (float*)d_out;
  const int ngraphs = (in_sizes[0] / CIN) / NE;   // 8192
  const int nblocks = ngraphs / PG;               // 1024 = 4 blocks/CU exactly
  gconv_kernel<<<nblocks, NTHREADS, 0, stream>>>(x, ew, Wrel, Wroot, bias, out);
}

// Round 4
// 40.278 us; speedup vs baseline: 1.2625x; 1.2625x over previous
//
#include <hip/hip_runtime.h>

#define NE 19
#define CIN 64
#define PG 8
#define ROWS (NE*PG)      // 152 rows per block
#define MTILES 10         // ceil(152/16)
#define NTHREADS 256
#define STRIDE 256        // bytes per LDS row: 128 bf16 (mixed 0-63, raw 64-127) or 64 f32 (bounce)

typedef float f32x4 __attribute__((ext_vector_type(4)));
typedef unsigned short u16x2 __attribute__((ext_vector_type(2)));
typedef unsigned short u16x4 __attribute__((ext_vector_type(4)));
typedef unsigned short u16x8 __attribute__((ext_vector_type(8)));
typedef __bf16 bf16x8 __attribute__((ext_vector_type(8)));

__device__ __forceinline__ unsigned short f2bf(float f) {
  unsigned u = __builtin_bit_cast(unsigned, f);
  return (unsigned short)((u + 0x7FFFu + ((u >> 16) & 1u)) >> 16);
}
__device__ __forceinline__ float bf2f(unsigned short h) {
  return __builtin_bit_cast(float, (unsigned)h << 16);
}
__device__ __forceinline__ int swz(int row, int byteoff) {
  return row * STRIDE + (byteoff ^ ((row & 7) << 4));
}

__global__ __launch_bounds__(NTHREADS, 2) void gconv_kernel(
    const float* __restrict__ x, const float* __restrict__ ew,
    const float* __restrict__ Wrel, const float* __restrict__ Wroot,
    const float* __restrict__ bias, float* __restrict__ out)
{
  __shared__ __align__(16) unsigned char xc[ROWS * STRIDE];  // 38912 B
  __shared__ __align__(16) float Ap[NE][20];                 // 1520 B, col 19 zero-padded

  const int t = threadIdx.x;
  const int lane = t & 63;
  const int wv = t >> 6;
  const int row0 = blockIdx.x * ROWS;
  const float* xg = x + (long long)row0 * CIN;

  // Phase 0: A[i][j] = softplus(ew[j*19+i]), padded to 20 cols (col 19 = 0)
  for (int e = t; e < NE * 20; e += NTHREADS) {
    int i = e / 20, j = e % 20;
    float v = 0.0f;
    if (j < NE) {
      float z = ew[j * NE + i];
      v = fmaxf(z, 0.0f) + log1pf(expf(-fabsf(z)));
    }
    Ap[i][j] = v;
  }

  // Phase A: stage raw x -> xc bytes [128,256) as bf16, coalesced
  #pragma unroll
  for (int p = 0; p < 10; ++p) {
    int q = p * NTHREADS + t;
    if (q < ROWS * 16) {
      int r = q >> 4, c = q & 15;
      f32x4 v = *(const f32x4*)(xg + q * 4);
      u16x4 h;
      h[0]=f2bf(v[0]); h[1]=f2bf(v[1]); h[2]=f2bf(v[2]); h[3]=f2bf(v[3]);
      *(u16x4*)(&xc[swz(r, 128 + c * 8)]) = h;
    }
  }
  __syncthreads();   // bar1: raw x + Ap visible

  // Phase B: mix -> xc bytes [0,128). Thread = (graph g=t>>5, ch pair c2=t&31).
  // x[j] held in regs (19 ds_read_b32); A read as b128 row chunks (broadcast).
  {
    const int g = t >> 5, c2 = t & 31;
    const int rb = g * NE;
    float xr0[20], xr1[20];
    #pragma unroll
    for (int j = 0; j < NE; ++j) {
      u16x2 v = *(const u16x2*)(&xc[swz(rb + j, 128 + c2 * 4)]);
      xr0[j] = bf2f(v[0]); xr1[j] = bf2f(v[1]);
    }
    xr0[19] = 0.f; xr1[19] = 0.f;
    float acc0[NE], acc1[NE];
    #pragma unroll
    for (int i = 0; i < NE; ++i) { acc0[i] = 0.f; acc1[i] = 0.f; }
    #pragma unroll 1
    for (int jc = 0; jc < 5; ++jc) {
      #pragma unroll
      for (int i = 0; i < NE; ++i) {
        f32x4 a4 = *(const f32x4*)(&Ap[i][jc * 4]);
        #pragma unroll
        for (int k = 0; k < 4; ++k) {
          acc0[i] = fmaf(a4[k], xr0[jc * 4 + k], acc0[i]);
          acc1[i] = fmaf(a4[k], xr1[jc * 4 + k], acc1[i]);
        }
      }
    }
    #pragma unroll
    for (int i = 0; i < NE; ++i) {
      u16x2 h; h[0] = f2bf(acc0[i]); h[1] = f2bf(acc1[i]);
      *(u16x2*)(&xc[swz(rb + i, c2 * 4)]) = h;
    }
  }
  __syncthreads();   // bar2: mixed cols visible

  // B fragments (block-uniform, L2-hot). Wc[k][n]: k<64 -> Wrel[n][k] (mixed
  // channels), k>=64 -> Wroot[n][k-64] (raw channels).
  u16x8 bfrag[4][4];
  float biasv[4];
  {
    const int jl = lane & 15;
    const int k0 = (lane >> 4) * 8;
    #pragma unroll
    for (int nt = 0; nt < 4; ++nt) biasv[nt] = bias[nt * 16 + jl];
    #pragma unroll
    for (int kt = 0; kt < 4; ++kt) {
      const float* Wsrc = (kt < 2) ? Wrel : Wroot;
      const float* p = Wsrc + ((kt & 1) * 32 + k0);
      #pragma unroll
      for (int nt = 0; nt < 4; ++nt) {
        const float* q = p + (nt * 16 + jl) * CIN;
        f32x4 a = *(const f32x4*)q;
        f32x4 b = *(const f32x4*)(q + 4);
        u16x8 h;
        h[0]=f2bf(a[0]); h[1]=f2bf(a[1]); h[2]=f2bf(a[2]); h[3]=f2bf(a[3]);
        h[4]=f2bf(b[0]); h[5]=f2bf(b[1]); h[6]=f2bf(b[2]); h[7]=f2bf(b[3]);
        bfrag[kt][nt] = h;
      }
    }
  }

  // GEMM: XC[152x128] @ Wc[128x64] -> f32 bounce back into xc (full 256B rows).
  // Waves own disjoint row-tiles; same-wave LDS ops are in-order -> race-free.
  const int lr = lane & 15;
  const int hg = lane >> 4;
  for (int mt = wv; mt < MTILES; mt += 4) {
    const int r0 = mt * 16;
    int rr = r0 + lr; if (rr >= ROWS) rr = ROWS - 1;   // dup row; discarded on write
    u16x8 af[4];
    #pragma unroll
    for (int kt = 0; kt < 4; ++kt)
      af[kt] = *(const u16x8*)(&xc[swz(rr, kt * 64 + hg * 16)]);
    f32x4 acc[4];
    #pragma unroll
    for (int nt = 0; nt < 4; ++nt) { acc[nt][0]=0.f; acc[nt][1]=0.f; acc[nt][2]=0.f; acc[nt][3]=0.f; }
    #pragma unroll
    for (int kt = 0; kt < 4; ++kt)
      #pragma unroll
      for (int nt = 0; nt < 4; ++nt)
        acc[nt] = __builtin_amdgcn_mfma_f32_16x16x32_bf16(
            __builtin_bit_cast(bf16x8, af[kt]),
            __builtin_bit_cast(bf16x8, bfrag[kt][nt]), acc[nt], 0, 0, 0);
    // D: col = nt*16+lr, row = r0+hg*4+b -> f32 at byte (col*4)^swz
    #pragma unroll
    for (int nt = 0; nt < 4; ++nt)
      #pragma unroll
      for (int b = 0; b < 4; ++b) {
        int row = r0 + hg * 4 + b;
        if (row < ROWS)
          *(float*)(&xc[swz(row, (nt * 16 + lr) * 4)]) = acc[nt][b] + biasv[nt];
      }
  }
  __syncthreads();   // bar3: bounce complete

  // Epilogue: coalesced f32x4 stores (1 KB contiguous per wave instruction)
  #pragma unroll
  for (int p = 0; p < 10; ++p) {
    int q = p * NTHREADS + t;
    if (q < ROWS * 16) {
      int r = q >> 4, c = q & 15;
      f32x4 v = *(const f32x4*)(&xc[swz(r, c * 16)]);
      *(f32x4*)(out + ((long long)row0 + r) * CIN + c * 4) = v;
    }
  }
}

extern "C" void kernel_launch(void* const* d_in, const int* in_sizes, int n_in,
                              void* d_out, int out_size, void* d_ws, size_t ws_size,
                              hipStream_t stream) {
  const float* x    = (const float*)d_in[0];
  const float* ew   = (const float*)d_in[1];
  const float* Wrel = (const float*)d_in[2];
  const float* Wroot= (const float*)d_in[3];
  const float* bias = (const float*)d_in[4];
  float* out = (float*)d_out;
  const int ngraphs = (in_sizes[0] / CIN) / NE;   // 8192
  const int nblocks = ngraphs / PG;               // 1024
  gconv_kernel<<<nblocks, NTHREADS, 0, stream>>>(x, ew, Wrel, Wroot, bias, out);
}